// Round 1
// baseline (3912.093 us; speedup 1.0000x reference)
//
#include <hip/hip_runtime.h>
#include <math.h>

#define B_ 32
#define T_ 20
#define H_ 256
#define F_ 512
#define NT_ 640

__device__ __forceinline__ float sigf(float x){ return 1.f/(1.f+__expf(-x)); }
__device__ __forceinline__ float lrelu(float x){ return x>0.f ? x : 0.2f*x; }
__device__ __forceinline__ float dot4(float4 a, float4 b){
  return fmaf(a.x,b.x, fmaf(a.y,b.y, fmaf(a.z,b.z, a.w*b.w)));
}

// Wc = w_ih + w_hh   (262144 floats, as float4)
__global__ void k_wc(const float* __restrict__ wih, const float* __restrict__ whh,
                     float* __restrict__ Wc){
  int i = blockIdx.x*256 + threadIdx.x;
  float4 a = ((const float4*)wih)[i];
  float4 b = ((const float4*)whh)[i];
  ((float4*)Wc)[i] = make_float4(a.x+b.x, a.y+b.y, a.z+b.z, a.w+b.w);
}

// bias1 = b_ih + b_hh ; bias0 = init_inp @ w_ih.T + bias1
__global__ void k_bias(const float* __restrict__ wih, const float* __restrict__ bih,
                       const float* __restrict__ bhh, const float* __restrict__ init_inp,
                       float* __restrict__ bias0, float* __restrict__ bias1){
  __shared__ __align__(16) float xs[H_];
  int tid = threadIdx.x;
  xs[tid] = init_inp[tid];
  __syncthreads();
  int j = blockIdx.x*256 + tid;
  const float4* wr = (const float4*)(wih + (size_t)j*H_);
  const float4* xx = (const float4*)xs;
  float acc = 0.f;
  #pragma unroll 8
  for(int k=0;k<H_/4;k++) acc += dot4(wr[k], xx[k]);
  float b1 = bih[j] + bhh[j];
  bias1[j] = b1;
  bias0[j] = acc + b1;
}

// out[b][j] = z[b] . W[j] + bias[j]   (h0 / c0)
__global__ void k_rowfc(const float* __restrict__ z, const float* __restrict__ W,
                        const float* __restrict__ bias, float* __restrict__ out){
  __shared__ __align__(16) float zs[H_];
  int b = blockIdx.x, j = threadIdx.x;
  zs[j] = z[b*H_ + j];
  __syncthreads();
  const float4* wr = (const float4*)(W + (size_t)j*H_);
  const float4* zz = (const float4*)zs;
  float acc = bias[j];
  #pragma unroll 8
  for(int k=0;k<H_/4;k++) acc += dot4(wr[k], zz[k]);
  out[b*H_+j] = acc;
}

__global__ void k_zero(float* p, int n){
  int i = blockIdx.x*256 + threadIdx.x;
  if(i<n) p[i]=0.f;
}

// one LSTM step: gates = hprev @ W.T + bias ; update c, write h
// grid (4 jgroups, 32 batch), block 256
__global__ void k_lstm(const float* __restrict__ hprev, float* __restrict__ c,
                       const float* __restrict__ W, const float* __restrict__ bias,
                       float* __restrict__ hout){
  __shared__ __align__(16) float hs[H_];
  __shared__ float gs[4][64];
  int b = blockIdx.y, jg = blockIdx.x, tid = threadIdx.x;
  hs[tid] = hprev[b*H_ + tid];
  __syncthreads();
  int g = tid>>6, jj = tid&63;
  int row = g*H_ + jg*64 + jj;
  const float4* wr = (const float4*)(W + (size_t)row*H_);
  const float4* hh = (const float4*)hs;
  float acc = bias[row];
  #pragma unroll 8
  for(int k=0;k<H_/4;k++) acc += dot4(wr[k], hh[k]);
  gs[g][jj] = acc;
  __syncthreads();
  if(tid < 64){
    int j = jg*64 + tid;
    float iv = gs[0][tid], fv = gs[1][tid], gv = gs[2][tid], ov = gs[3][tid];
    int ci = b*H_ + j;
    float cn = sigf(fv)*c[ci] + sigf(iv)*tanhf(gv);
    c[ci] = cn;
    hout[b*H_ + j] = sigf(ov)*tanhf(cn);
  }
}

// feats[n][f] = leaky(outs[t][b] . w[f] + bias[f]),  n = b*T+t. grid (2, 640)
__global__ void k_fcout(const float* __restrict__ outs, const float* __restrict__ w,
                        const float* __restrict__ bias, float* __restrict__ feats){
  __shared__ __align__(16) float hs[H_];
  int n = blockIdx.y; int b = n/T_, t = n - b*T_;
  int tid = threadIdx.x;
  hs[tid] = outs[(t*B_ + b)*H_ + tid];
  __syncthreads();
  int f = blockIdx.x*256 + tid;
  const float4* wr = (const float4*)(w + (size_t)f*H_);
  const float4* hh = (const float4*)hs;
  float acc = bias[f];
  #pragma unroll 8
  for(int k=0;k<H_/4;k++) acc += dot4(wr[k], hh[k]);
  feats[n*F_ + f] = lrelu(acc);
}

// fc1[n][oc] = leaky(feats[n] . w[oc] + b[oc]); block: 256 thr, 4 oc-rows x 8 n
// grid (4 ocg, 80 ngroups)
__global__ __launch_bounds__(256) void k_cnnfc(const float* __restrict__ feats,
    const float* __restrict__ w, const float* __restrict__ bias, float* __restrict__ out){
  __shared__ __align__(16) float fe[8*F_];
  int ocg = blockIdx.x, ng = blockIdx.y, tid = threadIdx.x;
  const float4* src = (const float4*)(feats + (size_t)ng*8*F_);
  float4* dst = (float4*)fe;
  for(int i=tid;i<8*F_/4;i+=256) dst[i] = src[i];
  __syncthreads();
  int oc0 = ocg*1024 + tid;
  const float4* w0 = (const float4*)(w + (size_t)(oc0      )*F_);
  const float4* w1 = (const float4*)(w + (size_t)(oc0+256 )*F_);
  const float4* w2 = (const float4*)(w + (size_t)(oc0+512 )*F_);
  const float4* w3 = (const float4*)(w + (size_t)(oc0+768 )*F_);
  float acc[4][8];
  #pragma unroll
  for(int i=0;i<4;i++){
    float bv = bias[oc0 + i*256];
    #pragma unroll
    for(int nn=0;nn<8;nn++) acc[i][nn]=bv;
  }
  for(int k=0;k<F_/4;k++){
    float4 wv0=w0[k], wv1=w1[k], wv2=w2[k], wv3=w3[k];
    #pragma unroll
    for(int nn=0;nn<8;nn++){
      float4 f = ((const float4*)(fe + nn*F_))[k];
      acc[0][nn] += dot4(wv0,f);
      acc[1][nn] += dot4(wv1,f);
      acc[2][nn] += dot4(wv2,f);
      acc[3][nn] += dot4(wv3,f);
    }
  }
  #pragma unroll
  for(int i=0;i<4;i++)
    #pragma unroll
    for(int nn=0;nn<8;nn++)
      out[(size_t)(ng*8+nn)*4096 + ocg*1024 + i*256 + tid] = lrelu(acc[i][nn]);
}

// ConvTranspose2d k=4 s=2 p=1.  out[oy=2iy+ky-1, ox=2ix+kx-1] += in*w[ic][oc][ky][kx]
// Thread: 2x2 output tile at (2ty,2tx) for Ko consecutive oc. Zero-masked 3x3 input window.
// block 256 = Lg lanegroups * Tt tiles; grid.x = OS*TS, grid.y = N
template<int IC, int OC, int IH, int Tt, int Lg, int Ko, bool FINAL>
__global__ __launch_bounds__(256) void k_deconv(const float* __restrict__ in,
    const float* __restrict__ w, float* __restrict__ out,
    float* __restrict__ ssum, float* __restrict__ ssq, const float* __restrict__ fb){
  static_assert(Tt*Lg == 256, "block mismatch");
  constexpr int IW = IH, OW = 2*IH;
  constexpr int NTILE = IH*IW;
  constexpr int OS = OC/(Lg*Ko);
  int bx = blockIdx.x;
  int os = bx % OS, ts = bx / OS;
  int n = blockIdx.y, tid = threadIdx.x;
  int lg = tid / Tt, t = tid % Tt;
  int tile = ts*Tt + t;
  int ty = tile / IW, tx = tile % IW;
  int oc0 = os*(Lg*Ko) + lg*Ko;

  const float* inb = in + (size_t)n*IC*NTILE;
  int offs[3][3]; float msk[3][3];
  #pragma unroll
  for(int dy=0;dy<3;dy++){
    int iy = ty-1+dy; bool vy = (iy>=0)&&(iy<IH);
    #pragma unroll
    for(int dx=0;dx<3;dx++){
      int ix = tx-1+dx; bool vx = (ix>=0)&&(ix<IW);
      offs[dy][dx] = (vy&&vx) ? (iy*IW+ix) : 0;
      msk[dy][dx]  = (vy&&vx) ? 1.f : 0.f;
    }
  }
  float acc[Ko][2][2];
  #pragma unroll
  for(int ko=0;ko<Ko;ko++)
    #pragma unroll
    for(int r=0;r<2;r++){ acc[ko][r][0]=0.f; acc[ko][r][1]=0.f; }

  for(int ic=0; ic<IC; ic++){
    const float* p = inb + ic*NTILE;
    float v[3][3];
    #pragma unroll
    for(int dy=0;dy<3;dy++)
      #pragma unroll
      for(int dx=0;dx<3;dx++)
        v[dy][dx] = p[offs[dy][dx]] * msk[dy][dx];
    const float4* wr = (const float4*)(w + ((size_t)ic*OC + oc0)*16);
    #pragma unroll
    for(int ko=0;ko<Ko;ko++){
      float4 w0=wr[ko*4+0], w1=wr[ko*4+1], w2=wr[ko*4+2], w3=wr[ko*4+3];
      float wv[16] = {w0.x,w0.y,w0.z,w0.w, w1.x,w1.y,w1.z,w1.w,
                      w2.x,w2.y,w2.z,w2.w, w3.x,w3.y,w3.z,w3.w};
      #pragma unroll
      for(int r=0;r<2;r++)
        #pragma unroll
        for(int s2=0;s2<2;s2++)
          #pragma unroll
          for(int a=0;a<2;a++)
            #pragma unroll
            for(int b2=0;b2<2;b2++)
              acc[ko][r][s2] = fmaf(v[a+r][b2+s2], wv[(3-2*a-r)*4 + (3-2*b2-s2)], acc[ko][r][s2]);
    }
  }

  float* ob = out + (size_t)n*OC*4*NTILE;
  if constexpr (FINAL){
    float fbv = fb[0];
    #pragma unroll
    for(int r=0;r<2;r++)
      #pragma unroll
      for(int s2=0;s2<2;s2++){
        float vv = acc[0][r][s2] + fbv;
        ob[(2*ty+r)*OW + (2*tx+s2)] = 1.f/(1.f+__expf(-vv));
      }
  } else {
    constexpr int RW = (Tt<64)?Tt:64;
    #pragma unroll
    for(int ko=0;ko<Ko;ko++){
      float s_=0.f, q_=0.f;
      #pragma unroll
      for(int r=0;r<2;r++)
        #pragma unroll
        for(int s2=0;s2<2;s2++){
          float vv = acc[ko][r][s2];
          ob[(size_t)(oc0+ko)*4*NTILE + (2*ty+r)*OW + (2*tx+s2)] = vv;
          s_ += vv; q_ = fmaf(vv,vv,q_);
        }
      #pragma unroll
      for(int m=1;m<RW;m<<=1){ s_ += __shfl_xor(s_,m,RW); q_ += __shfl_xor(q_,m,RW); }
      if((t & (RW-1))==0){ atomicAdd(&ssum[oc0+ko], s_); atomicAdd(&ssq[oc0+ko], q_); }
    }
  }
}

// in-place BN(training stats) + leaky, float4-vectorized. x layout (N, OC, SP)
template<int OC, int SP>
__global__ void k_bn(float* __restrict__ x, const float* __restrict__ ssum,
                     const float* __restrict__ ssq, const float* __restrict__ g,
                     const float* __restrict__ be, int n4){
  int i = blockIdx.x*256 + threadIdx.x;
  if(i >= n4) return;
  int c = ((i*4)/SP) % OC;
  const float inv_cnt = 1.f/(640.f*SP);
  float m = ssum[c]*inv_cnt;
  float var = ssq[c]*inv_cnt - m*m;
  float sc = g[c]*rsqrtf(var + 1e-5f);
  float sh = be[c] - m*sc;
  float4 xv = ((float4*)x)[i];
  xv.x = lrelu(fmaf(xv.x, sc, sh));
  xv.y = lrelu(fmaf(xv.y, sc, sh));
  xv.z = lrelu(fmaf(xv.z, sc, sh));
  xv.w = lrelu(fmaf(xv.w, sc, sh));
  ((float4*)x)[i] = xv;
}

extern "C" void kernel_launch(void* const* d_in, const int* in_sizes, int n_in,
                              void* d_out, int out_size, void* d_ws, size_t ws_size,
                              hipStream_t stream){
  const float* z       = (const float*)d_in[0];
  const float* fhw     = (const float*)d_in[1];
  const float* fhb     = (const float*)d_in[2];
  const float* fcw     = (const float*)d_in[3];
  const float* fcb     = (const float*)d_in[4];
  const float* wih     = (const float*)d_in[5];
  const float* bih     = (const float*)d_in[6];
  const float* whh     = (const float*)d_in[7];
  const float* bhh     = (const float*)d_in[8];
  const float* init_inp= (const float*)d_in[9];
  const float* fow     = (const float*)d_in[10];
  const float* fob     = (const float*)d_in[11];
  const float* cfw     = (const float*)d_in[12];
  const float* cfb     = (const float*)d_in[13];
  const float* dw0     = (const float*)d_in[14];
  const float* g0      = (const float*)d_in[15];
  const float* be0     = (const float*)d_in[16];
  const float* dw1     = (const float*)d_in[17];
  const float* g1      = (const float*)d_in[18];
  const float* be1     = (const float*)d_in[19];
  const float* dw2     = (const float*)d_in[20];
  const float* g2      = (const float*)d_in[21];
  const float* be2     = (const float*)d_in[22];
  const float* fw      = (const float*)d_in[23];
  const float* fb      = (const float*)d_in[24];

  float* ws    = (float*)d_ws;
  float* conv2 = ws;                 // 640*32*1024 = 20971520
  float* conv1 = ws + 20971520;      // 640*64*256  = 10485760
  float* conv0 = ws + 31457280;      // 640*128*64  =  5242880
  float* fc1   = ws + 36700160;      // 640*4096    =  2621440
  float* feats = ws + 39321600;      // 640*512     =   327680
  float* outs  = ws + 39649280;      // 20*32*256   =   163840
  float* Wc    = ws + 39813120;      // 1024*256    =   262144
  float* bias0 = ws + 40075264;      // 1024
  float* bias1 = ws + 40076288;      // 1024
  float* h0    = ws + 40077312;      // 8192
  float* cbuf  = ws + 40085504;      // 8192
  float* stats = ws + 40093696;      // 448
  float* sum0 = stats,     *sq0 = stats+128;
  float* sum1 = stats+256, *sq1 = stats+320;
  float* sum2 = stats+384, *sq2 = stats+416;

  hipLaunchKernelGGL(k_wc,    dim3(256), dim3(256), 0, stream, wih, whh, Wc);
  hipLaunchKernelGGL(k_bias,  dim3(4),   dim3(256), 0, stream, wih, bih, bhh, init_inp, bias0, bias1);
  hipLaunchKernelGGL(k_rowfc, dim3(32),  dim3(256), 0, stream, z, fhw, fhb, h0);
  hipLaunchKernelGGL(k_rowfc, dim3(32),  dim3(256), 0, stream, z, fcw, fcb, cbuf);
  hipLaunchKernelGGL(k_zero,  dim3(2),   dim3(256), 0, stream, stats, 448);

  for(int t=0;t<T_;t++){
    const float* W  = (t==0) ? whh   : Wc;
    const float* bs = (t==0) ? bias0 : bias1;
    const float* hp = (t==0) ? h0    : outs + (t-1)*B_*H_;
    hipLaunchKernelGGL(k_lstm, dim3(4,32), dim3(256), 0, stream, hp, cbuf, W, bs, outs + t*B_*H_);
  }

  hipLaunchKernelGGL(k_fcout, dim3(2,NT_), dim3(256), 0, stream, outs, fow, fob, feats);
  hipLaunchKernelGGL(k_cnnfc, dim3(4,80),  dim3(256), 0, stream, feats, cfw, cfb, fc1);

  hipLaunchKernelGGL((k_deconv<256,128,4,16,16,8,false>), dim3(1,NT_), dim3(256), 0, stream,
                     fc1, dw0, conv0, sum0, sq0, nullptr);
  hipLaunchKernelGGL((k_bn<128,64>),   dim3(5120),  dim3(256), 0, stream, conv0, sum0, sq0, g0, be0, 1310720);
  hipLaunchKernelGGL((k_deconv<128,64,8,64,4,8,false>), dim3(2,NT_), dim3(256), 0, stream,
                     conv0, dw1, conv1, sum1, sq1, nullptr);
  hipLaunchKernelGGL((k_bn<64,256>),   dim3(10240), dim3(256), 0, stream, conv1, sum1, sq1, g1, be1, 2621440);
  hipLaunchKernelGGL((k_deconv<64,32,16,64,4,8,false>), dim3(4,NT_), dim3(256), 0, stream,
                     conv1, dw2, conv2, sum2, sq2, nullptr);
  hipLaunchKernelGGL((k_bn<32,1024>),  dim3(20480), dim3(256), 0, stream, conv2, sum2, sq2, g2, be2, 5242880);
  hipLaunchKernelGGL((k_deconv<32,1,32,256,1,1,true>), dim3(4,NT_), dim3(256), 0, stream,
                     conv2, fw, (float*)d_out, nullptr, nullptr, fb);
}

// Round 2
// 2421.819 us; speedup vs baseline: 1.6154x; 1.6154x over previous
//
#include <hip/hip_runtime.h>
#include <math.h>

#define B_ 32
#define T_ 20
#define H_ 256
#define F_ 512
#define NT_ 640

__device__ __forceinline__ float sigf(float x){ return 1.f/(1.f+__expf(-x)); }
__device__ __forceinline__ float lrelu(float x){ return x>0.f ? x : 0.2f*x; }
__device__ __forceinline__ float dot4(float4 a, float4 b){
  return fmaf(a.x,b.x, fmaf(a.y,b.y, fmaf(a.z,b.z, a.w*b.w)));
}

// Wc = w_ih + w_hh   (262144 floats, as float4)
__global__ void k_wc(const float* __restrict__ wih, const float* __restrict__ whh,
                     float* __restrict__ Wc){
  int i = blockIdx.x*256 + threadIdx.x;
  float4 a = ((const float4*)wih)[i];
  float4 b = ((const float4*)whh)[i];
  ((float4*)Wc)[i] = make_float4(a.x+b.x, a.y+b.y, a.z+b.z, a.w+b.w);
}

// bias1 = b_ih + b_hh ; bias0 = init_inp @ w_ih.T + bias1
__global__ void k_bias(const float* __restrict__ wih, const float* __restrict__ bih,
                       const float* __restrict__ bhh, const float* __restrict__ init_inp,
                       float* __restrict__ bias0, float* __restrict__ bias1){
  __shared__ __align__(16) float xs[H_];
  int tid = threadIdx.x;
  xs[tid] = init_inp[tid];
  __syncthreads();
  int j = blockIdx.x*256 + tid;
  const float4* wr = (const float4*)(wih + (size_t)j*H_);
  const float4* xx = (const float4*)xs;
  float acc = 0.f;
  #pragma unroll 8
  for(int k=0;k<H_/4;k++) acc += dot4(wr[k], xx[k]);
  float b1 = bih[j] + bhh[j];
  bias1[j] = b1;
  bias0[j] = acc + b1;
}

// out[b][j] = z[b] . W[j] + bias[j]   (h0 / c0)
__global__ void k_rowfc(const float* __restrict__ z, const float* __restrict__ W,
                        const float* __restrict__ bias, float* __restrict__ out){
  __shared__ __align__(16) float zs[H_];
  int b = blockIdx.x, j = threadIdx.x;
  zs[j] = z[b*H_ + j];
  __syncthreads();
  const float4* wr = (const float4*)(W + (size_t)j*H_);
  const float4* zz = (const float4*)zs;
  float acc = bias[j];
  #pragma unroll 8
  for(int k=0;k<H_/4;k++) acc += dot4(wr[k], zz[k]);
  out[b*H_+j] = acc;
}

__global__ void k_zero(float* p, int n){
  int i = blockIdx.x*256 + threadIdx.x;
  if(i<n) p[i]=0.f;
}

// one LSTM step: gates = hprev @ W.T + bias ; update c, write h
// grid (4 jgroups, 32 batch), block 256
__global__ void k_lstm(const float* __restrict__ hprev, float* __restrict__ c,
                       const float* __restrict__ W, const float* __restrict__ bias,
                       float* __restrict__ hout){
  __shared__ __align__(16) float hs[H_];
  __shared__ float gs[4][64];
  int b = blockIdx.y, jg = blockIdx.x, tid = threadIdx.x;
  hs[tid] = hprev[b*H_ + tid];
  __syncthreads();
  int g = tid>>6, jj = tid&63;
  int row = g*H_ + jg*64 + jj;
  const float4* wr = (const float4*)(W + (size_t)row*H_);
  const float4* hh = (const float4*)hs;
  float acc = bias[row];
  #pragma unroll 8
  for(int k=0;k<H_/4;k++) acc += dot4(wr[k], hh[k]);
  gs[g][jj] = acc;
  __syncthreads();
  if(tid < 64){
    int j = jg*64 + tid;
    float iv = gs[0][tid], fv = gs[1][tid], gv = gs[2][tid], ov = gs[3][tid];
    int ci = b*H_ + j;
    float cn = sigf(fv)*c[ci] + sigf(iv)*tanhf(gv);
    c[ci] = cn;
    hout[b*H_ + j] = sigf(ov)*tanhf(cn);
  }
}

// feats[n][f] = leaky(outs[t][b] . w[f] + bias[f]),  n = b*T+t. grid (2, 640)
__global__ void k_fcout(const float* __restrict__ outs, const float* __restrict__ w,
                        const float* __restrict__ bias, float* __restrict__ feats){
  __shared__ __align__(16) float hs[H_];
  int n = blockIdx.y; int b = n/T_, t = n - b*T_;
  int tid = threadIdx.x;
  hs[tid] = outs[(t*B_ + b)*H_ + tid];
  __syncthreads();
  int f = blockIdx.x*256 + tid;
  const float4* wr = (const float4*)(w + (size_t)f*H_);
  const float4* hh = (const float4*)hs;
  float acc = bias[f];
  #pragma unroll 8
  for(int k=0;k<H_/4;k++) acc += dot4(wr[k], hh[k]);
  feats[n*F_ + f] = lrelu(acc);
}

// fc1[n][oc] = leaky(feats[n] . w[oc] + b[oc]); block: 256 thr, 4 oc-rows x 8 n
// grid (4 ocg, 80 ngroups)
__global__ __launch_bounds__(256) void k_cnnfc(const float* __restrict__ feats,
    const float* __restrict__ w, const float* __restrict__ bias, float* __restrict__ out){
  __shared__ __align__(16) float fe[8*F_];
  int ocg = blockIdx.x, ng = blockIdx.y, tid = threadIdx.x;
  const float4* src = (const float4*)(feats + (size_t)ng*8*F_);
  float4* dst = (float4*)fe;
  for(int i=tid;i<8*F_/4;i+=256) dst[i] = src[i];
  __syncthreads();
  int oc0 = ocg*1024 + tid;
  const float4* w0 = (const float4*)(w + (size_t)(oc0      )*F_);
  const float4* w1 = (const float4*)(w + (size_t)(oc0+256 )*F_);
  const float4* w2 = (const float4*)(w + (size_t)(oc0+512 )*F_);
  const float4* w3 = (const float4*)(w + (size_t)(oc0+768 )*F_);
  float acc[4][8];
  #pragma unroll
  for(int i=0;i<4;i++){
    float bv = bias[oc0 + i*256];
    #pragma unroll
    for(int nn=0;nn<8;nn++) acc[i][nn]=bv;
  }
  for(int k=0;k<F_/4;k++){
    float4 wv0=w0[k], wv1=w1[k], wv2=w2[k], wv3=w3[k];
    #pragma unroll
    for(int nn=0;nn<8;nn++){
      float4 f = ((const float4*)(fe + nn*F_))[k];
      acc[0][nn] += dot4(wv0,f);
      acc[1][nn] += dot4(wv1,f);
      acc[2][nn] += dot4(wv2,f);
      acc[3][nn] += dot4(wv3,f);
    }
  }
  #pragma unroll
  for(int i=0;i<4;i++)
    #pragma unroll
    for(int nn=0;nn<8;nn++)
      out[(size_t)(ng*8+nn)*4096 + ocg*1024 + i*256 + tid] = lrelu(acc[i][nn]);
}

// ---------------------------------------------------------------------------
// v2 deconv: ConvTranspose2d k=4 s=2 p=1, direct gather form.
// Block: 256 thr = Lg lanegroups x Tt tiles; NB batch images per block staged
// in LDS (coalesced float4). Each thread: 2x2 output tile x Ko oc x NB n.
// Weight float4 loads (lanegroup-uniform broadcast) amortized over NB images.
// grid.x = OCG*TS (oc-split x tile-split), grid.y = 640/NB.
template<int IC, int OC, int IH, int NB, int Tt, int Lg, int Ko>
__global__ __launch_bounds__(256,2) void k_deconv2(const float* __restrict__ in,
    const float* __restrict__ w, float* __restrict__ out,
    float* __restrict__ ssum, float* __restrict__ ssq){
  static_assert(Tt*Lg == 256, "block mismatch");
  constexpr int IW = IH, OW = 2*IH;
  constexpr int S = IH*IW;
  constexpr int OCG = OC/(Lg*Ko);
  constexpr int TS = S/Tt;
  __shared__ float lin[NB*IC*S];

  int bx = blockIdx.x;
  int os = bx % OCG, ts = bx / OCG;
  int n0 = blockIdx.y*NB;
  int tid = threadIdx.x;

  // stage NB full images into LDS (contiguous in global: [n][ic][pos])
  {
    const float4* src = (const float4*)(in + (size_t)n0*IC*S);
    float4* dst = (float4*)lin;
    constexpr int NV = NB*IC*S/4;
    #pragma unroll
    for(int i=0;i<NV/256;i++) dst[tid + i*256] = src[tid + i*256];
  }
  __syncthreads();

  int lg = tid / Tt, t = tid % Tt;
  int tile = ts*Tt + t;
  int ty = tile / IW, tx = tile % IW;
  int oc0 = os*(Lg*Ko) + lg*Ko;

  int offs[3][3]; float msk[3][3];
  #pragma unroll
  for(int dy=0;dy<3;dy++){
    int iy = ty-1+dy; bool vy = (iy>=0)&&(iy<IH);
    #pragma unroll
    for(int dx=0;dx<3;dx++){
      int ix = tx-1+dx; bool vx = (ix>=0)&&(ix<IW);
      offs[dy][dx] = (vy&&vx) ? (iy*IW+ix) : 0;
      msk[dy][dx]  = (vy&&vx) ? 1.f : 0.f;
    }
  }

  float acc[Ko][NB][2][2];
  #pragma unroll
  for(int ko=0;ko<Ko;ko++)
    #pragma unroll
    for(int nb=0;nb<NB;nb++)
      #pragma unroll
      for(int r=0;r<2;r++){ acc[ko][nb][r][0]=0.f; acc[ko][nb][r][1]=0.f; }

  for(int ic=0; ic<IC; ic++){
    float v[NB][3][3];
    #pragma unroll
    for(int nb=0;nb<NB;nb++){
      const float* p = lin + (nb*IC + ic)*S;
      #pragma unroll
      for(int dy=0;dy<3;dy++)
        #pragma unroll
        for(int dx=0;dx<3;dx++)
          v[nb][dy][dx] = p[offs[dy][dx]] * msk[dy][dx];
    }
    const float4* wr = (const float4*)(w + ((size_t)ic*OC + oc0)*16);
    #pragma unroll
    for(int ko=0;ko<Ko;ko++){
      float4 w0=wr[ko*4+0], w1=wr[ko*4+1], w2=wr[ko*4+2], w3=wr[ko*4+3];
      float wv[16] = {w0.x,w0.y,w0.z,w0.w, w1.x,w1.y,w1.z,w1.w,
                      w2.x,w2.y,w2.z,w2.w, w3.x,w3.y,w3.z,w3.w};
      #pragma unroll
      for(int nb=0;nb<NB;nb++)
        #pragma unroll
        for(int r=0;r<2;r++)
          #pragma unroll
          for(int s2=0;s2<2;s2++)
            #pragma unroll
            for(int a=0;a<2;a++)
              #pragma unroll
              for(int b2=0;b2<2;b2++)
                acc[ko][nb][r][s2] = fmaf(v[nb][a+r][b2+s2], wv[(3-2*a-r)*4 + (3-2*b2-s2)], acc[ko][nb][r][s2]);
    }
  }

  constexpr int RW = (Tt<64)?Tt:64;
  #pragma unroll
  for(int ko=0;ko<Ko;ko++){
    float s_=0.f, q_=0.f;
    #pragma unroll
    for(int nb=0;nb<NB;nb++){
      float* ob = out + ((size_t)(n0+nb)*OC + oc0+ko)*4*S;
      #pragma unroll
      for(int r=0;r<2;r++)
        #pragma unroll
        for(int s2=0;s2<2;s2++){
          float vv = acc[ko][nb][r][s2];
          ob[(2*ty+r)*OW + (2*tx+s2)] = vv;
          s_ += vv; q_ = fmaf(vv,vv,q_);
        }
    }
    #pragma unroll
    for(int m=1;m<RW;m<<=1){ s_ += __shfl_xor(s_,m,RW); q_ += __shfl_xor(q_,m,RW); }
    if((t & (RW-1))==0){ atomicAdd(&ssum[oc0+ko], s_); atomicAdd(&ssq[oc0+ko], q_); }
  }
}

// Final ConvTranspose (32->1) + sigmoid, original direct form.
template<int IC, int OC, int IH, int Tt, int Lg, int Ko, bool FINAL>
__global__ __launch_bounds__(256) void k_deconv(const float* __restrict__ in,
    const float* __restrict__ w, float* __restrict__ out,
    float* __restrict__ ssum, float* __restrict__ ssq, const float* __restrict__ fb){
  static_assert(Tt*Lg == 256, "block mismatch");
  constexpr int IW = IH, OW = 2*IH;
  constexpr int NTILE = IH*IW;
  constexpr int OS = OC/(Lg*Ko);
  int bx = blockIdx.x;
  int os = bx % OS, ts = bx / OS;
  int n = blockIdx.y, tid = threadIdx.x;
  int lg = tid / Tt, t = tid % Tt;
  int tile = ts*Tt + t;
  int ty = tile / IW, tx = tile % IW;
  int oc0 = os*(Lg*Ko) + lg*Ko;

  const float* inb = in + (size_t)n*IC*NTILE;
  int offs[3][3]; float msk[3][3];
  #pragma unroll
  for(int dy=0;dy<3;dy++){
    int iy = ty-1+dy; bool vy = (iy>=0)&&(iy<IH);
    #pragma unroll
    for(int dx=0;dx<3;dx++){
      int ix = tx-1+dx; bool vx = (ix>=0)&&(ix<IW);
      offs[dy][dx] = (vy&&vx) ? (iy*IW+ix) : 0;
      msk[dy][dx]  = (vy&&vx) ? 1.f : 0.f;
    }
  }
  float acc[Ko][2][2];
  #pragma unroll
  for(int ko=0;ko<Ko;ko++)
    #pragma unroll
    for(int r=0;r<2;r++){ acc[ko][r][0]=0.f; acc[ko][r][1]=0.f; }

  for(int ic=0; ic<IC; ic++){
    const float* p = inb + ic*NTILE;
    float v[3][3];
    #pragma unroll
    for(int dy=0;dy<3;dy++)
      #pragma unroll
      for(int dx=0;dx<3;dx++)
        v[dy][dx] = p[offs[dy][dx]] * msk[dy][dx];
    const float4* wr = (const float4*)(w + ((size_t)ic*OC + oc0)*16);
    #pragma unroll
    for(int ko=0;ko<Ko;ko++){
      float4 w0=wr[ko*4+0], w1=wr[ko*4+1], w2=wr[ko*4+2], w3=wr[ko*4+3];
      float wv[16] = {w0.x,w0.y,w0.z,w0.w, w1.x,w1.y,w1.z,w1.w,
                      w2.x,w2.y,w2.z,w2.w, w3.x,w3.y,w3.z,w3.w};
      #pragma unroll
      for(int r=0;r<2;r++)
        #pragma unroll
        for(int s2=0;s2<2;s2++)
          #pragma unroll
          for(int a=0;a<2;a++)
            #pragma unroll
            for(int b2=0;b2<2;b2++)
              acc[ko][r][s2] = fmaf(v[a+r][b2+s2], wv[(3-2*a-r)*4 + (3-2*b2-s2)], acc[ko][r][s2]);
    }
  }

  float* ob = out + (size_t)n*OC*4*NTILE;
  if constexpr (FINAL){
    float fbv = fb[0];
    #pragma unroll
    for(int r=0;r<2;r++)
      #pragma unroll
      for(int s2=0;s2<2;s2++){
        float vv = acc[0][r][s2] + fbv;
        ob[(2*ty+r)*OW + (2*tx+s2)] = 1.f/(1.f+__expf(-vv));
      }
  } else {
    constexpr int RW = (Tt<64)?Tt:64;
    #pragma unroll
    for(int ko=0;ko<Ko;ko++){
      float s_=0.f, q_=0.f;
      #pragma unroll
      for(int r=0;r<2;r++)
        #pragma unroll
        for(int s2=0;s2<2;s2++){
          float vv = acc[ko][r][s2];
          ob[(size_t)(oc0+ko)*4*NTILE + (2*ty+r)*OW + (2*tx+s2)] = vv;
          s_ += vv; q_ = fmaf(vv,vv,q_);
        }
      #pragma unroll
      for(int m=1;m<RW;m<<=1){ s_ += __shfl_xor(s_,m,RW); q_ += __shfl_xor(q_,m,RW); }
      if((t & (RW-1))==0){ atomicAdd(&ssum[oc0+ko], s_); atomicAdd(&ssq[oc0+ko], q_); }
    }
  }
}

// in-place BN(training stats) + leaky, float4-vectorized. x layout (N, OC, SP)
template<int OC, int SP>
__global__ void k_bn(float* __restrict__ x, const float* __restrict__ ssum,
                     const float* __restrict__ ssq, const float* __restrict__ g,
                     const float* __restrict__ be, int n4){
  int i = blockIdx.x*256 + threadIdx.x;
  if(i >= n4) return;
  int c = ((i*4)/SP) % OC;
  const float inv_cnt = 1.f/(640.f*SP);
  float m = ssum[c]*inv_cnt;
  float var = ssq[c]*inv_cnt - m*m;
  float sc = g[c]*rsqrtf(var + 1e-5f);
  float sh = be[c] - m*sc;
  float4 xv = ((float4*)x)[i];
  xv.x = lrelu(fmaf(xv.x, sc, sh));
  xv.y = lrelu(fmaf(xv.y, sc, sh));
  xv.z = lrelu(fmaf(xv.z, sc, sh));
  xv.w = lrelu(fmaf(xv.w, sc, sh));
  ((float4*)x)[i] = xv;
}

extern "C" void kernel_launch(void* const* d_in, const int* in_sizes, int n_in,
                              void* d_out, int out_size, void* d_ws, size_t ws_size,
                              hipStream_t stream){
  const float* z       = (const float*)d_in[0];
  const float* fhw     = (const float*)d_in[1];
  const float* fhb     = (const float*)d_in[2];
  const float* fcw     = (const float*)d_in[3];
  const float* fcb     = (const float*)d_in[4];
  const float* wih     = (const float*)d_in[5];
  const float* bih     = (const float*)d_in[6];
  const float* whh     = (const float*)d_in[7];
  const float* bhh     = (const float*)d_in[8];
  const float* init_inp= (const float*)d_in[9];
  const float* fow     = (const float*)d_in[10];
  const float* fob     = (const float*)d_in[11];
  const float* cfw     = (const float*)d_in[12];
  const float* cfb     = (const float*)d_in[13];
  const float* dw0     = (const float*)d_in[14];
  const float* g0      = (const float*)d_in[15];
  const float* be0     = (const float*)d_in[16];
  const float* dw1     = (const float*)d_in[17];
  const float* g1      = (const float*)d_in[18];
  const float* be1     = (const float*)d_in[19];
  const float* dw2     = (const float*)d_in[20];
  const float* g2      = (const float*)d_in[21];
  const float* be2     = (const float*)d_in[22];
  const float* fw      = (const float*)d_in[23];
  const float* fb      = (const float*)d_in[24];

  float* ws    = (float*)d_ws;
  float* conv2 = ws;                 // 640*32*1024 = 20971520
  float* conv1 = ws + 20971520;      // 640*64*256  = 10485760
  float* conv0 = ws + 31457280;      // 640*128*64  =  5242880
  float* fc1   = ws + 36700160;      // 640*4096    =  2621440
  float* feats = ws + 39321600;      // 640*512     =   327680
  float* outs  = ws + 39649280;      // 20*32*256   =   163840
  float* Wc    = ws + 39813120;      // 1024*256    =   262144
  float* bias0 = ws + 40075264;      // 1024
  float* bias1 = ws + 40076288;      // 1024
  float* h0    = ws + 40077312;      // 8192
  float* cbuf  = ws + 40085504;      // 8192
  float* stats = ws + 40093696;      // 448
  float* sum0 = stats,     *sq0 = stats+128;
  float* sum1 = stats+256, *sq1 = stats+320;
  float* sum2 = stats+384, *sq2 = stats+416;

  hipLaunchKernelGGL(k_wc,    dim3(256), dim3(256), 0, stream, wih, whh, Wc);
  hipLaunchKernelGGL(k_bias,  dim3(4),   dim3(256), 0, stream, wih, bih, bhh, init_inp, bias0, bias1);
  hipLaunchKernelGGL(k_rowfc, dim3(32),  dim3(256), 0, stream, z, fhw, fhb, h0);
  hipLaunchKernelGGL(k_rowfc, dim3(32),  dim3(256), 0, stream, z, fcw, fcb, cbuf);
  hipLaunchKernelGGL(k_zero,  dim3(2),   dim3(256), 0, stream, stats, 448);

  for(int t=0;t<T_;t++){
    const float* W  = (t==0) ? whh   : Wc;
    const float* bs = (t==0) ? bias0 : bias1;
    const float* hp = (t==0) ? h0    : outs + (t-1)*B_*H_;
    hipLaunchKernelGGL(k_lstm, dim3(4,32), dim3(256), 0, stream, hp, cbuf, W, bs, outs + t*B_*H_);
  }

  hipLaunchKernelGGL(k_fcout, dim3(2,NT_), dim3(256), 0, stream, outs, fow, fob, feats);
  hipLaunchKernelGGL(k_cnnfc, dim3(4,80),  dim3(256), 0, stream, feats, cfw, cfb, fc1);

  // deconv0: IC=256 OC=128 IH=4  | NB=2 Tt=16 Lg=16 Ko=2 -> OCG=4, TS=1, grid(4,320)
  hipLaunchKernelGGL((k_deconv2<256,128,4,2,16,16,2>), dim3(4,320), dim3(256), 0, stream,
                     fc1, dw0, conv0, sum0, sq0);
  hipLaunchKernelGGL((k_bn<128,64>),   dim3(5120),  dim3(256), 0, stream, conv0, sum0, sq0, g0, be0, 1310720);
  // deconv1: IC=128 OC=64 IH=8  | NB=2 Tt=64 Lg=4 Ko=4 -> OCG=4, TS=1, grid(4,320)
  hipLaunchKernelGGL((k_deconv2<128,64,8,2,64,4,4>), dim3(4,320), dim3(256), 0, stream,
                     conv0, dw1, conv1, sum1, sq1);
  hipLaunchKernelGGL((k_bn<64,256>),   dim3(10240), dim3(256), 0, stream, conv1, sum1, sq1, g1, be1, 2621440);
  // deconv2: IC=64 OC=32 IH=16 | NB=1 Tt=64 Lg=4 Ko=4 -> OCG=2, TS=4, grid(8,640)
  hipLaunchKernelGGL((k_deconv2<64,32,16,1,64,4,4>), dim3(8,640), dim3(256), 0, stream,
                     conv1, dw2, conv2, sum2, sq2);
  hipLaunchKernelGGL((k_bn<32,1024>),  dim3(20480), dim3(256), 0, stream, conv2, sum2, sq2, g2, be2, 5242880);
  hipLaunchKernelGGL((k_deconv<32,1,32,256,1,1,true>), dim3(4,640), dim3(256), 0, stream,
                     conv2, fw, (float*)d_out, nullptr, nullptr, fb);
}